// Round 6
// baseline (1346.252 us; speedup 1.0000x reference)
//
#include <hip/hip_runtime.h>
#include <math.h>

#define S_LEN 100
#define NCAT  18

typedef __attribute__((ext_vector_type(8)))  short  short8;
typedef __attribute__((ext_vector_type(16))) float  floatx16;

#define AT_LOADU(p)   __hip_atomic_load((p), __ATOMIC_RELAXED, __HIP_MEMORY_SCOPE_AGENT)
#define AT_STORE(p,v) __hip_atomic_store((p),(v), __ATOMIC_RELAXED, __HIP_MEMORY_SCOPE_AGENT)

// ws byte layout:
//   H0[lstm][buf]: bf16 [64 b][256 k] at (lstm*2+buf)*32768        (0..131071)
//   H1[lstm][buf]: same              at 131072 + (lstm*2+buf)*32768 (..262143)
//   barrier: group g in {0,1}: arr = 262144 + g*1024 (32 slots x 16B), flag at arr+512
// All H + barrier traffic via relaxed agent-scope atomics (sc1, IF-coherent; R5-proven).

struct Params {
  const int* ivu; const int* ivo;
  const float* lro; const float* lru;
  const float* VE;
  const float* W[4][2];   // [inst][part]; inst: bit0=lstm, bit1=layer; part0=Wih, part1=Whh
  const float* b0[4]; const float* b1[4];
  const float* roW; const float* rob;
  const float* ruW; const float* rub;
  float* ws; float* out;
};

__device__ __forceinline__ unsigned short f2bf(float f) {
  unsigned u = __builtin_bit_cast(unsigned, f);
  u += 0x7FFFu + ((u >> 16) & 1u);          // RNE
  return (unsigned short)(u >> 16);
}
__device__ __forceinline__ float bf2f(unsigned short h) {
  unsigned u = ((unsigned)h) << 16;
  return __builtin_bit_cast(float, u);
}
__device__ __forceinline__ short8 pack64(unsigned long long l0, unsigned long long l1) {
  union { unsigned long long u[2]; short8 s; } c;
  c.u[0] = l0; c.u[1] = l1;
  return c.s;
}

__global__ void init_k(unsigned* bar, float* out) {
  bar[threadIdx.x] = 0u;                    // 512 dwords = 2 KB barrier area
  if (threadIdx.x == 0) out[64] = 0.f;      // KL accumulator (out poisoned 0xAA)
}

// 32-WG barrier: arrival = release store to own 16B slot; master lanes 0..31
// poll one slot each; flag release. No fences (sc1 coherence; R5-proven).
__device__ __forceinline__ void group_barrier(unsigned* arr, unsigned* flag,
                                              unsigned epoch, int gb, bool master) {
  __syncthreads();   // drains vmcnt(0): all h stores IF-visible before arrival
  if (threadIdx.x == 0) AT_STORE(arr + gb * 4, epoch);
  if (master && threadIdx.x < 32) {
    while (AT_LOADU(arr + threadIdx.x * 4) < epoch) __builtin_amdgcn_s_sleep(1);
    if (threadIdx.x == 0) AT_STORE(flag, epoch);
  }
  if (threadIdx.x == 0) {
    while (AT_LOADU(flag) < epoch) __builtin_amdgcn_s_sleep(1);
  }
  __syncthreads();
}

// 64 WGs x 256 thr. WG (inst, wg) owns m-units [wg*16, wg*16+16) x 4 gates
// = 64 W-rows, K=512. 4 waves: wave=(jt<<1)|bt computes D tile [32 j x 32 b]
// via 32 chained mfma_f32_32x32x16_bf16.
__global__ __launch_bounds__(256, 1) void lstm_all(Params P) {
  __shared__ short  Wlds[64 * 520];     // 66.6 KB bf16 weights, row-major, stride 520
  __shared__ float  gatebuf[64 * 64];   // 16 KB: [jrow = g*16+m][b]
  __shared__ float  cst[16 * 64];       // c-state [m][b]
  __shared__ float  bias_l[64];

  const int tid  = threadIdx.x;
  const int lane = tid & 63;
  const int wave = tid >> 6;            // 0..3
  const int blk  = blockIdx.x;
  const int inst = blk >> 4;            // 0=vu-L0 1=vo-L0 2=vu-L1 3=vo-L1
  const int wg   = blk & 15;
  const int lstm = inst & 1;
  const int layer = inst >> 1;
  const int gb   = layer * 16 + wg;     // 0..31 within lstm group
  const bool master = (gb == 0);

  char* wsb = (char*)P.ws;
  unsigned* arr  = (unsigned*)(wsb + 262144 + lstm * 1024);
  unsigned* flag = (unsigned*)(wsb + 262144 + lstm * 1024 + 512);

  // ---- stage weights -> LDS bf16 (one time; reread 101x) ----
  {
    const int jrow = tid >> 2;          // 0..63 = g*16+m
    const int q    = tid & 3;
    const int R    = (jrow >> 4) * 256 + wg * 16 + (jrow & 15);
    const float* wih = P.W[inst][0] + (size_t)R * 256;
    const float* whh = P.W[inst][1] + (size_t)R * 256;
    short* dst = &Wlds[jrow * 520];
    for (int k = q * 128; k < q * 128 + 128; k += 4) {
      const float* src = (k < 256) ? (wih + k) : (whh + (k - 256));
      float4 v = *(const float4*)src;
      dst[k + 0] = (short)f2bf(v.x); dst[k + 1] = (short)f2bf(v.y);
      dst[k + 2] = (short)f2bf(v.z); dst[k + 3] = (short)f2bf(v.w);
    }
  }
  if (tid < 64) {
    const int R = (tid >> 4) * 256 + wg * 16 + (tid & 15);
    bias_l[tid] = P.b0[inst][R] + P.b1[inst][R];
  }
  for (int i = tid; i < 16 * 64; i += 256) cst[i] = 0.f;

  // ---- zero all H buffers: 64 WG x 256 thr x 16 B = 262144 B exactly ----
  {
    unsigned long long* z = (unsigned long long*)wsb;
    const int i = (blk * 256 + tid) * 2;
    AT_STORE(z + i, 0ull);
    AT_STORE(z + i + 1, 0ull);
  }

  const int* __restrict__ idxp = lstm ? P.ivo : P.ivu;
  const int jt = wave >> 1, bt = wave & 1;
  const int bl   = bt * 32 + (lane & 31);   // batch column this lane owns
  const int half = lane >> 5;               // k-half within fragment
  const short* Arow = &Wlds[(jt * 32 + (lane & 31)) * 520 + half * 8];

  group_barrier(arr, flag, 1u, gb, master);

  for (int t = 0; t <= S_LEN; ++t) {
    const bool active = (layer == 0) ? (t < S_LEN) : (t >= 1);
    if (active) {
      const int cur = t & 1, prv = (t + 1) & 1;
      floatx16 acc;
      #pragma unroll
      for (int r = 0; r < 16; ++r) acc[r] = 0.f;

      // B-frag row pointers ([b][256 k] bf16 rows = 64 u64)
      const unsigned long long* lo64 =
          (const unsigned long long*)(wsb + (size_t)(lstm * 2 + prv) * 32768) + bl * 64;  // h0_{t-1}/y0
      const unsigned long long* hi64 = (layer == 0)
          ? lo64                                                                            // h0_{t-1}
          : (const unsigned long long*)(wsb + 131072 + (size_t)(lstm * 2 + cur) * 32768) + bl * 64; // h1_{t-2}

      if (layer == 0) {
        // K 0..255: embedding gather from VE (fp32 -> bf16)
        const int row = idxp[bl * S_LEN + t];
        const float* __restrict__ vr = P.VE + (size_t)row * 256 + half * 8;
        #pragma unroll
        for (int s = 0; s < 16; ++s) {
          short8 a = *(const short8*)(Arow + s * 16);
          float4 v0 = *(const float4*)(vr + s * 16);
          float4 v1 = *(const float4*)(vr + s * 16 + 4);
          short8 b;
          b[0] = (short)f2bf(v0.x); b[1] = (short)f2bf(v0.y);
          b[2] = (short)f2bf(v0.z); b[3] = (short)f2bf(v0.w);
          b[4] = (short)f2bf(v1.x); b[5] = (short)f2bf(v1.y);
          b[6] = (short)f2bf(v1.z); b[7] = (short)f2bf(v1.w);
          acc = __builtin_amdgcn_mfma_f32_32x32x16_bf16(a, b, acc, 0, 0, 0);
        }
      } else {
        // K 0..255: y0_{t-1} from H0[prv]
        #pragma unroll
        for (int s = 0; s < 16; ++s) {
          short8 a = *(const short8*)(Arow + s * 16);
          unsigned long long l0 = AT_LOADU(lo64 + s * 4 + half * 2);
          unsigned long long l1 = AT_LOADU(lo64 + s * 4 + half * 2 + 1);
          acc = __builtin_amdgcn_mfma_f32_32x32x16_bf16(a, pack64(l0, l1), acc, 0, 0, 0);
        }
      }
      // K 256..511: recurrent h
      #pragma unroll
      for (int s = 16; s < 32; ++s) {
        short8 a = *(const short8*)(Arow + s * 16);
        unsigned long long l0 = AT_LOADU(hi64 + (s - 16) * 4 + half * 2);
        unsigned long long l1 = AT_LOADU(hi64 + (s - 16) * 4 + half * 2 + 1);
        acc = __builtin_amdgcn_mfma_f32_32x32x16_bf16(a, pack64(l0, l1), acc, 0, 0, 0);
      }

      // D -> gatebuf: col = lane&31 (b), row = (r&3)+8*(r>>2)+4*half
      #pragma unroll
      for (int r = 0; r < 16; ++r) {
        const int row = (r & 3) + 8 * (r >> 2) + 4 * half;
        gatebuf[(jt * 32 + row) * 64 + bl] = acc[r];
      }
      __syncthreads();

      // gate reduction + activations: thread = (b = tid&63, mq = tid>>6), 4 m each
      {
        const int b = tid & 63, mq = tid >> 6;
        unsigned long long hpack = 0ull;
        #pragma unroll
        for (int i = 0; i < 4; ++i) {
          const int m = mq * 4 + i;
          const float g0 = gatebuf[(0 * 16 + m) * 64 + b] + bias_l[0 * 16 + m];
          const float g1 = gatebuf[(1 * 16 + m) * 64 + b] + bias_l[1 * 16 + m];
          const float g2 = gatebuf[(2 * 16 + m) * 64 + b] + bias_l[2 * 16 + m];
          const float g3 = gatebuf[(3 * 16 + m) * 64 + b] + bias_l[3 * 16 + m];
          const float ig = 1.f / (1.f + __expf(-g0));
          const float fg = 1.f / (1.f + __expf(-g1));
          const float gg = tanhf(g2);
          const float og = 1.f / (1.f + __expf(-g3));
          const float c  = fg * cst[m * 64 + b] + ig * gg;
          cst[m * 64 + b] = c;
          const float hv = og * tanhf(c);
          hpack |= ((unsigned long long)f2bf(hv)) << (16 * i);
        }
        unsigned long long* hout = (layer == 0)
            ? (unsigned long long*)(wsb + (size_t)(lstm * 2 + cur) * 32768)
            : (unsigned long long*)(wsb + 131072 + (size_t)(lstm * 2 + prv) * 32768);
        AT_STORE(hout + b * 64 + wg * 4 + mq, hpack);   // k = wg*16 + mq*4 .. +3 at batch b
      }
    }
    if (t < S_LEN) group_barrier(arr, flag, (unsigned)(t + 2), gb, master);
  }
}

// head: 64 blocks (one per batch) x 64 threads
__global__ __launch_bounds__(64) void head_kernel(Params P) {
  __shared__ float enc[256];
  __shared__ float dec[NCAT];
  const int b = blockIdx.x, t = threadIdx.x;
  char* wsb = (char*)P.ws;
  const unsigned short* hvu = (const unsigned short*)(wsb + 131072 + 1 * 32768) + b * 256; // H1 vu buf1
  const unsigned short* hvo = (const unsigned short*)(wsb + 131072 + 3 * 32768) + b * 256; // H1 vo buf1

  for (int m = t; m < 256; m += 64) {
    float s = P.rob[m];
    for (int j = 0; j < NCAT; ++j) s = fmaf(P.lro[b * NCAT + j], P.roW[m * NCAT + j], s);
    enc[m] = fmaxf(s, 0.f);
  }
  __syncthreads();
  for (int n = 0; n < NCAT; ++n) {
    const float* __restrict__ wr = P.ruW + n * 768;
    float s = 0.f;
    for (int k = t; k < 256; k += 64) {
      s = fmaf(bf2f(hvu[k]), wr[k], s);
      s = fmaf(bf2f(hvo[k]), wr[256 + k], s);
      s = fmaf(enc[k],       wr[512 + k], s);
    }
    for (int off = 32; off; off >>= 1) s += __shfl_down(s, off, 64);
    if (t == 0) dec[n] = s + P.rub[n];
  }
  __syncthreads();
  if (t == 0) {
    float M = dec[0];
    for (int j = 1; j < NCAT; ++j) M = fmaxf(M, dec[j]);
    float Ssum = 0.f;
    for (int j = 0; j < NCAT; ++j) Ssum += expf(dec[j] - M);
    const float lse = M + logf(Ssum);
    float neg = 0.f, kl = 0.f;
    for (int j = 0; j < NCAT; ++j) {
      const float lp = dec[j] - lse;
      const float q  = P.lru[b * NCAT + j];
      neg -= q * lp;
      kl  += q * (logf(q) - lp);
    }
    P.out[b] = neg;
    atomicAdd(&P.out[64], kl * 1.4426950408889634f * (1.f / 64.f));
  }
}

extern "C" void kernel_launch(void* const* d_in, const int* in_sizes, int n_in,
                              void* d_out, int out_size, void* d_ws, size_t ws_size,
                              hipStream_t stream) {
  Params P;
  P.ivu = (const int*)d_in[0];
  P.ivo = (const int*)d_in[1];
  P.lro = (const float*)d_in[2];
  if (in_sizes[3] >= in_sizes[4]) { P.VE = (const float*)d_in[3]; P.lru = (const float*)d_in[4]; }
  else                            { P.VE = (const float*)d_in[4]; P.lru = (const float*)d_in[3]; }
  // inst: 0 = vu-L0, 1 = vo-L0, 2 = vu-L1, 3 = vo-L1
  P.W[0][0] = (const float*)d_in[5];  P.W[0][1] = (const float*)d_in[6];
  P.b0[0]   = (const float*)d_in[7];  P.b1[0]   = (const float*)d_in[8];
  P.W[2][0] = (const float*)d_in[9];  P.W[2][1] = (const float*)d_in[10];
  P.b0[2]   = (const float*)d_in[11]; P.b1[2]   = (const float*)d_in[12];
  P.W[1][0] = (const float*)d_in[13]; P.W[1][1] = (const float*)d_in[14];
  P.b0[1]   = (const float*)d_in[15]; P.b1[1]   = (const float*)d_in[16];
  P.W[3][0] = (const float*)d_in[17]; P.W[3][1] = (const float*)d_in[18];
  P.b0[3]   = (const float*)d_in[19]; P.b1[3]   = (const float*)d_in[20];
  P.roW = (const float*)d_in[21]; P.rob = (const float*)d_in[22];
  P.ruW = (const float*)d_in[23]; P.rub = (const float*)d_in[24];
  P.ws  = (float*)d_ws;
  P.out = (float*)d_out;

  unsigned* bar = (unsigned*)((char*)d_ws + 262144);
  init_k<<<1, 512, 0, stream>>>(bar, P.out);

  void* args[] = { &P };
  hipLaunchCooperativeKernel((void*)lstm_all, dim3(64), dim3(256), args, 0, stream);
  head_kernel<<<64, 64, 0, stream>>>(P);
}